// Round 4
// baseline (351.081 us; speedup 1.0000x reference)
//
#include <hip/hip_runtime.h>

typedef __bf16 bf16x8 __attribute__((ext_vector_type(8)));
typedef float  f32x4  __attribute__((ext_vector_type(4)));
typedef unsigned short u16x8 __attribute__((ext_vector_type(8)));

// Problem constants
constexpr int BB    = 16;
constexpr int TT    = 12;
constexpr int NN    = 307;
constexpr int TN    = TT * NN;        // 3684
constexpr int ROWSX = BB * TT * NN;   // 58944
constexpr int ROWSH = BB * NN;        // 4912
constexpr int SST1  = 3712;           // sag row stride (464 x b128 chunks)
constexpr int SSTR  = 3840;           // xnT row stride
constexpr float SCALE = 0.125f;

__device__ __forceinline__ float wred_sum(float v) {
#pragma unroll
    for (int m = 32; m > 0; m >>= 1) v += __shfl_xor(v, m, 64);
    return v;
}

// ---------------------------------------------------------------------------
// Fold q/k projections: dg = q.k = qt.x_ + c
// ---------------------------------------------------------------------------
__global__ void fold_k(const float* __restrict__ qw, const float* __restrict__ qb,
                       const float* __restrict__ kw, const float* __restrict__ kb,
                       float* __restrict__ M, float* __restrict__ b2,
                       float* __restrict__ vv, float* __restrict__ cc) {
    int e = blockIdx.x, d = threadIdx.x;
    float acc = 0.f;
    for (int dp = 0; dp < 64; ++dp) acc += qw[dp * 64 + e] * kw[dp * 64 + d];
    M[e * 64 + d] = acc;
    float vp = wred_sum(qw[d * 64 + e] * kb[d]);
    if (d == 0) vv[e] = vp;
    if (e == 0) {
        float b = 0.f;
        for (int dp = 0; dp < 64; ++dp) b += qb[dp] * kw[dp * 64 + d];
        b2[d] = b;
        float cp = wred_sum(qb[d] * kb[d]);
        if (d == 0) *cc = cp;
    }
}

// ---------------------------------------------------------------------------
// LayerNorm -> xnb (bf16) + y32 (fp32, t==11 slab)
// ---------------------------------------------------------------------------
__global__ __launch_bounds__(256) void ln_k(const float* __restrict__ x,
                                            const float* __restrict__ g,
                                            const float* __restrict__ b,
                                            __bf16* __restrict__ xnb,
                                            float* __restrict__ y32) {
    int w = threadIdx.x >> 6, l = threadIdx.x & 63;
    int r = blockIdx.x * 4 + w;
    if (r >= ROWSX) return;
    float val = x[r * 64 + l];
    float mu  = wred_sum(val) * (1.f / 64.f);
    float dv  = val - mu;
    float var = wred_sum(dv * dv) * (1.f / 64.f);
    float xv  = dv * rsqrtf(var + 1e-5f) * g[l] + b[l];
    xnb[(size_t)r * 64 + l] = (__bf16)xv;
    int t = (r / NN) % TT;
    if (t == TT - 1) {
        int bbv = r / (NN * TT), n = r % NN;
        y32[(bbv * NN + n) * 64 + l] = xv;
    }
}

// ---------------------------------------------------------------------------
// Transpose xnb[b,j,d] -> xnT[b,d,j] (stride SSTR; j>=TN zero within tiles)
// ---------------------------------------------------------------------------
__global__ __launch_bounds__(256) void t_k(const __bf16* __restrict__ xnb,
                                           __bf16* __restrict__ xnT) {
    __shared__ unsigned short tile[64][65];
    int bb = blockIdx.y, j0 = blockIdx.x * 64, t = threadIdx.x;
    const unsigned short* src = (const unsigned short*)xnb;
    unsigned short* dst = (unsigned short*)xnT;
#pragma unroll
    for (int i = 0; i < 16; ++i) {
        int f = t + 256 * i, jr = f >> 6, dc = f & 63;
        int j = j0 + jr;
        tile[jr][dc] = (j < TN) ? src[((size_t)bb * TN + j) * 64 + dc] : (unsigned short)0;
    }
    __syncthreads();
#pragma unroll
    for (int i = 0; i < 16; ++i) {
        int f = t + 256 * i, d = f >> 6, jj = f & 63;
        dst[((size_t)bb * 64 + d) * SSTR + j0 + jj] = tile[jj][d];
    }
}

// ---------------------------------------------------------------------------
// qt[row] = y_ @ M + b2 (bf16);  cq[row] = y_.v + cc
// ---------------------------------------------------------------------------
__global__ __launch_bounds__(256) void qt_k(const float* __restrict__ y32,
                                            const float* __restrict__ M,
                                            const float* __restrict__ b2,
                                            const float* __restrict__ vv,
                                            const float* __restrict__ ccp,
                                            __bf16* __restrict__ qtb,
                                            float* __restrict__ cq) {
    int w = threadIdx.x >> 6, l = threadIdx.x & 63;
    int rr = blockIdx.x * 4 + w;
    if (rr >= ROWSH) return;
    float y = y32[rr * 64 + l];
    float acc = b2[l];
#pragma unroll
    for (int e = 0; e < 64; ++e) acc += __shfl(y, e, 64) * M[e * 64 + l];
    qtb[(size_t)rr * 64 + l] = (__bf16)acc;
    float cp = wred_sum(y * vv[l]);
    if (l == 0) cq[rr] = cp + *ccp;
}

// ---------------------------------------------------------------------------
// Score GEMM via MFMA. stg tile staged LDS via coalesced float4 (latency
// overlapped with MFMA). Writes sag row stride SST1, zeros for j>=TN.
// ---------------------------------------------------------------------------
__global__ __launch_bounds__(256) void score_k(const __bf16* __restrict__ qtb,
                                               const float* __restrict__ cq,
                                               const __bf16* __restrict__ xnb,
                                               const float* __restrict__ stg,
                                               __bf16* __restrict__ sag) {
    __shared__ float sstg[64 * 132];   // 33 KB, stride 132 breaks conflicts
    int bb = blockIdx.z, n0 = blockIdx.y * 64, j0 = blockIdx.x * 128;
    int t = threadIdx.x;
    int w = t >> 6, lane = t & 63;
    int m16 = lane & 15, q4 = lane >> 4;

    // ---- stage stg tile [64n x 128j] fp32 -> LDS (coalesced float4) ----
#pragma unroll
    for (int i = 0; i < 8; ++i) {
        int flat = t + i * 256;            // 0..2047
        int row = flat >> 5, c4 = (flat & 31) * 4;
        int n = n0 + row;
        float4 v = {0.f, 0.f, 0.f, 0.f};
        if (n < NN) {
            size_t rb = (size_t)(bb * NN + n) * TN;
            int j = j0 + c4;
            if (j + 3 < TN) v = *(const float4*)(stg + rb + j);
            else {
                if (j + 0 < TN) v.x = stg[rb + j + 0];
                if (j + 1 < TN) v.y = stg[rb + j + 1];
                if (j + 2 < TN) v.z = stg[rb + j + 2];
                if (j + 3 < TN) v.w = stg[rb + j + 3];
            }
        }
        *(float4*)&sstg[row * 132 + c4] = v;
    }

    // ---- MFMA: 64n x 128j, K=64 ----
    const bf16x8* ap = (const bf16x8*)(qtb + ((size_t)bb * NN + n0 + w * 16 + m16) * 64);
    bf16x8 a0 = ap[q4], a1 = ap[q4 + 4];
    f32x4 acc[8];
#pragma unroll
    for (int jt = 0; jt < 8; ++jt) {
        const bf16x8* bp = (const bf16x8*)(xnb + ((size_t)bb * TN + j0 + jt * 16 + m16) * 64);
        bf16x8 b0 = bp[q4], b1 = bp[q4 + 4];
        f32x4 c = {0.f, 0.f, 0.f, 0.f};
        c = __builtin_amdgcn_mfma_f32_16x16x32_bf16(a0, b0, c, 0, 0, 0);
        c = __builtin_amdgcn_mfma_f32_16x16x32_bf16(a1, b1, c, 0, 0, 0);
        acc[jt] = c;
    }
    int nbase = n0 + w * 16 + q4 * 4;
    float cn[4];
#pragma unroll
    for (int r = 0; r < 4; ++r) {
        int n = nbase + r;
        cn[r] = (n < NN) ? cq[bb * NN + n] : 0.f;
    }
    __syncthreads();

    // ---- epilogue: sigmoid * stg * scale ----
#pragma unroll
    for (int r = 0; r < 4; ++r) {
        int n = nbase + r;
        if (n >= NN) continue;
        int nloc = w * 16 + q4 * 4 + r;
        size_t rb = ((size_t)bb * NN + n) * SST1;
#pragma unroll
        for (int jt = 0; jt < 8; ++jt) {
            int j = j0 + jt * 16 + m16;
            float sv = sstg[nloc * 132 + jt * 16 + m16];
            float dg = (acc[jt][r] + cn[r]) * SCALE;
            float s  = 1.f / (1.f + __expf(-dg));
            float wv = (j < TN) ? s * sv * SCALE : 0.f;
            sag[rb + j] = (__bf16)wv;
        }
    }
}

// ---------------------------------------------------------------------------
// Fused topk+softmax+PV+residual. Raw sag rows -> registers (global,
// coalesced). Exact threshold via 16-step binary search on bf16 key space
// (no LDS, no atomics). Normalized bf16 weights -> LDS once, PV via MFMA.
// ---------------------------------------------------------------------------
__global__ __launch_bounds__(256) void attn_k(const __bf16* __restrict__ sagB,
                                              const __bf16* __restrict__ xnT,
                                              const float* __restrict__ y32,
                                              const int* __restrict__ topk_p,
                                              float* __restrict__ h) {
    __shared__ unsigned short sg[8][3720];   // 59.5 KB (normalized weights)
    __shared__ float red[4][8][64];          // 8 KB
    int t = threadIdx.x;
    int bb = blockIdx.y, n0 = blockIdx.x * 8;
    int wid = t >> 6, lane = t & 63;
    const unsigned short* sagu = (const unsigned short*)sagB;

    int topkv = *topk_p;
    bool selAll = (topkv <= 0);
    int kk = 0;
    if (!selAll) {
        kk = (topkv < 5) ? topkv * NN : topkv;
        if (kk > TN) kk = TN;
    }

    // ---- preload this wave's 2 rows into registers (coalesced b128) ----
    u16x8 va[2][8];
#pragma unroll
    for (int rr = 0; rr < 2; ++rr) {
        int r = wid * 2 + rr, n = n0 + r;
        const u16x8* src = (const u16x8*)(sagu + (size_t)(bb * NN + n) * SST1);
#pragma unroll
        for (int ci = 0; ci < 8; ++ci) {
            int c = lane + (ci << 6);
            u16x8 v = {0, 0, 0, 0, 0, 0, 0, 0};
            if (n < NN && c < 464) v = src[c];
            va[rr][ci] = v;
        }
    }

    for (int rr = 0; rr < 2; ++rr) {
        int r = wid * 2 + rr;
        // row max (values >= 0: bf16 bit order = value order; pads are 0)
        int vmb = 0;
#pragma unroll
        for (int ci = 0; ci < 8; ++ci)
#pragma unroll
            for (int e = 0; e < 8; ++e) vmb = max(vmb, (int)va[rr][ci][e]);
#pragma unroll
        for (int m = 32; m > 0; m >>= 1) vmb = max(vmb, __shfl_xor(vmb, m, 64));
        float vmax = __uint_as_float(((unsigned)vmb) << 16);

        // exact kk-th largest via binary search: smallest T with cnt(>T) < kk
        unsigned thrb = 0;
        if (!selAll) {
            unsigned lo = 0, hi = 65535;
            while (lo < hi) {
                unsigned mid = (lo + hi) >> 1;
                int cnt = 0;
#pragma unroll
                for (int ci = 0; ci < 8; ++ci)
#pragma unroll
                    for (int e = 0; e < 8; ++e)
                        cnt += ((unsigned)va[rr][ci][e] > mid);
#pragma unroll
                for (int m = 32; m > 0; m >>= 1) cnt += __shfl_xor(cnt, m, 64);
                if (cnt < kk) hi = mid; else lo = mid + 1;
            }
            thrb = lo;
        }

        // sum pass: compute exp for selected, cache as bf16 in-place
        float local = 0.f;
#pragma unroll
        for (int ci = 0; ci < 8; ++ci) {
            int c = lane + (ci << 6);
            int nvv = (c < 460) ? 8 : ((c == 460) ? 4 : 0);
#pragma unroll
            for (int e = 0; e < 8; ++e) {
                unsigned u = va[rr][ci][e];
                bool sel = selAll ? (e < nvv) : (u > thrb);
                float ev = sel ? __expf(__uint_as_float(u << 16) - vmax) : 0.f;
                local += ev;
                __bf16 eb = (__bf16)ev;
                va[rr][ci][e] = *(unsigned short*)&eb;
            }
        }
        local = wred_sum(local);
        bool uni = !(local > 0.f);
        float inv = uni ? 0.f : 1.f / local;
        float uval = 1.f / (float)TN;

        // normalize + write to LDS (bf16)
#pragma unroll
        for (int ci = 0; ci < 8; ++ci) {
            int c = lane + (ci << 6);
            if (c >= 464) continue;
            int nvv = (c < 460) ? 8 : ((c == 460) ? 4 : 0);
            bf16x8 o;
#pragma unroll
            for (int e = 0; e < 8; ++e) {
                if (uni) o[e] = (e < nvv) ? (__bf16)uval : (__bf16)0.f;
                else {
                    unsigned short us = va[rr][ci][e];
                    float ev = (float)(*(__bf16*)&us);
                    o[e] = (__bf16)(ev * inv);
                }
            }
            *(bf16x8*)&sg[r][c * 8] = o;
        }
    }
    __syncthreads();

    // ---- PV: o[16][64] (rows 8..15 zero), K split across 4 waves ----
    int m16 = lane & 15, q4 = lane >> 4;
    bf16x8 zf;
#pragma unroll
    for (int e = 0; e < 8; ++e) zf[e] = (__bf16)0.f;
    f32x4 acc[4];
#pragma unroll
    for (int dt = 0; dt < 4; ++dt) acc[dt] = (f32x4){0.f, 0.f, 0.f, 0.f};
    const __bf16* bbase = xnT + (size_t)bb * 64 * SSTR;
    int kbase = wid * 928;
    for (int ks = 0; ks < 29; ++ks) {
        int k0 = kbase + ks * 32 + q4 * 8;
        bf16x8 a = zf;
        if (m16 < 8) a = *(const bf16x8*)&sg[m16][k0];
#pragma unroll
        for (int dt = 0; dt < 4; ++dt) {
            bf16x8 b = *(const bf16x8*)(bbase + (size_t)(dt * 16 + m16) * SSTR + k0);
            acc[dt] = __builtin_amdgcn_mfma_f32_16x16x32_bf16(a, b, acc[dt], 0, 0, 0);
        }
    }
#pragma unroll
    for (int dt = 0; dt < 4; ++dt)
#pragma unroll
        for (int r2 = 0; r2 < 4; ++r2) {
            int row = q4 * 4 + r2;
            if (row < 8) red[wid][row][dt * 16 + m16] = acc[dt][r2];
        }
    __syncthreads();
    // ---- cross-wave reduce + residual ----
    for (int i = t; i < 512; i += 256) {
        int row = i >> 6, col = i & 63;
        int n = n0 + row;
        if (n < NN) {
            float s = red[0][row][col] + red[1][row][col] + red[2][row][col] + red[3][row][col];
            size_t o = (size_t)(bb * NN + n) * 64 + col;
            h[o] = s + y32[o];
        }
    }
}

// ---------------------------------------------------------------------------
// FFN: out = h + (relu(LN(h)@fc1^T + b1)@fc2^T + b2)    16 rows/block
// ---------------------------------------------------------------------------
__global__ __launch_bounds__(256) void ffn_k(const float* __restrict__ h,
                                             const float* __restrict__ g,
                                             const float* __restrict__ bln,
                                             const float* __restrict__ fc1w,
                                             const float* __restrict__ fc1b,
                                             const float* __restrict__ fc2w,
                                             const float* __restrict__ fc2b,
                                             float* __restrict__ out) {
    __shared__ float zbuf[16 * 65];
    __shared__ float wbuf[256 * 65];
    __shared__ float abuf[16 * 257];
    int t = threadIdx.x;
    int r0 = blockIdx.x * 16;
    int w = t >> 6, l = t & 63;
    for (int q = 0; q < 4; ++q) {
        int rloc = w * 4 + q;
        float val = h[(r0 + rloc) * 64 + l];
        float mu  = wred_sum(val) * (1.f / 64.f);
        float dv  = val - mu;
        float var = wred_sum(dv * dv) * (1.f / 64.f);
        zbuf[rloc * 65 + l] = dv * rsqrtf(var + 1e-5f) * g[l] + bln[l];
    }
#pragma unroll
    for (int i = 0; i < 64; ++i) {
        int f = t + 256 * i, row = f >> 6, col = f & 63;
        wbuf[row * 65 + col] = fc1w[f];
    }
    __syncthreads();
    {
        int tr = t >> 6, tc = t & 63;
        float acc[4][4];
#pragma unroll
        for (int a = 0; a < 4; ++a)
#pragma unroll
            for (int c = 0; c < 4; ++c) acc[a][c] = 0.f;
#pragma unroll 4
        for (int d = 0; d < 64; ++d) {
            float av[4], bv[4];
#pragma unroll
            for (int ri = 0; ri < 4; ++ri) av[ri] = zbuf[(tr + 4 * ri) * 65 + d];
#pragma unroll
            for (int ci = 0; ci < 4; ++ci) bv[ci] = wbuf[(tc + 64 * ci) * 65 + d];
#pragma unroll
            for (int ri = 0; ri < 4; ++ri)
#pragma unroll
                for (int ci = 0; ci < 4; ++ci) acc[ri][ci] += av[ri] * bv[ci];
        }
#pragma unroll
        for (int ri = 0; ri < 4; ++ri)
#pragma unroll
            for (int ci = 0; ci < 4; ++ci) {
                int i = tc + 64 * ci;
                abuf[(tr + 4 * ri) * 257 + i] = fmaxf(acc[ri][ci] + fc1b[i], 0.f);
            }
    }
    __syncthreads();
#pragma unroll
    for (int i = 0; i < 64; ++i) {
        int f = t + 256 * i, row = f >> 8, col = f & 255;
        wbuf[row * 257 + col] = fc2w[f];
    }
    __syncthreads();
    {
        int tg = t >> 4, tc4 = t & 15;
        float acc2[4] = {0.f, 0.f, 0.f, 0.f};
#pragma unroll 8
        for (int k = 0; k < 256; ++k) {
            float a = abuf[tg * 257 + k];
#pragma unroll
            for (int ci = 0; ci < 4; ++ci) acc2[ci] += a * wbuf[(tc4 + 16 * ci) * 257 + k];
        }
#pragma unroll
        for (int ci = 0; ci < 4; ++ci) {
            int c = tc4 + 16 * ci;
            int row = r0 + tg;
            out[row * 64 + c] = h[row * 64 + c] + acc2[ci] + fc2b[c];
        }
    }
}

extern "C" void kernel_launch(void* const* d_in, const int* in_sizes, int n_in,
                              void* d_out, int out_size, void* d_ws, size_t ws_size,
                              hipStream_t stream) {
    const float* x    = (const float*)d_in[0];
    const float* stg  = (const float*)d_in[1];
    const int*   topk = (const int*)d_in[2];
    const float* qw   = (const float*)d_in[3];
    const float* qb   = (const float*)d_in[4];
    const float* kw   = (const float*)d_in[5];
    const float* kb   = (const float*)d_in[6];
    const float* lng  = (const float*)d_in[7];
    const float* lnb  = (const float*)d_in[8];
    const float* flng = (const float*)d_in[9];
    const float* flnb = (const float*)d_in[10];
    const float* fc1w = (const float*)d_in[11];
    const float* fc1b = (const float*)d_in[12];
    const float* fc2w = (const float*)d_in[13];
    const float* fc2b = (const float*)d_in[14];
    float* out = (float*)d_out;

    // Workspace layout (float units), ~55 MB total
    float* ws = (float*)d_ws;
    __bf16* xnb = (__bf16*)ws;                 // ROWSX*64 bf16 = 1,886,208 f
    float* p1   = ws + 1886208;
    __bf16* xnT = (__bf16*)p1;                 // 16*64*3840 bf16 = 1,966,080 f
    float* p2   = p1 + 1966080;
    __bf16* qtb = (__bf16*)p2;                 // 4928*64 bf16 = 157,696 f
    float* y32  = p2 + 157696;                 // 314,368 f
    float* cq   = y32 + 314368;                // 4,928 f
    float* M    = cq + 4928;                   // 4,096
    float* b2   = M + 4096;                    // 64
    float* vv   = b2 + 64;                     // 64
    float* cc   = vv + 64;                     // 16
    __bf16* sag = (__bf16*)(cc + 16);          // ROWSH*3712 bf16 = 9,116,672 f
    float* h    = (float*)sag + 9116672;       // 314,368 f

    fold_k<<<64, 64, 0, stream>>>(qw, qb, kw, kb, M, b2, vv, cc);
    ln_k<<<(ROWSX + 3) / 4, 256, 0, stream>>>(x, lng, lnb, xnb, y32);
    t_k<<<dim3((TN + 63) / 64, BB), 256, 0, stream>>>(xnb, xnT);
    qt_k<<<(ROWSH + 3) / 4, 256, 0, stream>>>(y32, M, b2, vv, cc, qtb, cq);
    score_k<<<dim3((TN + 127) / 128, (NN + 63) / 64, BB), 256, 0, stream>>>(qtb, cq, xnb, stg, sag);
    attn_k<<<dim3((NN + 7) / 8, BB), 256, 0, stream>>>(sag, xnT, y32, topk, h);
    ffn_k<<<ROWSH / 16, 256, 0, stream>>>(h, flng, flnb, fc1w, fc1b, fc2w, fc2b, out);
}

// Round 5
// 326.175 us; speedup vs baseline: 1.0764x; 1.0764x over previous
//
#include <hip/hip_runtime.h>

typedef __bf16 bf16x8 __attribute__((ext_vector_type(8)));
typedef float  f32x4  __attribute__((ext_vector_type(4)));
typedef unsigned short u16x8 __attribute__((ext_vector_type(8)));

// Problem constants
constexpr int BB    = 16;
constexpr int TT    = 12;
constexpr int NN    = 307;
constexpr int TN    = TT * NN;        // 3684
constexpr int ROWSX = BB * TT * NN;   // 58944
constexpr int ROWSH = BB * NN;        // 4912
constexpr int SST1  = 3712;           // sag row stride (464 x b128 chunks)
constexpr int SSTR  = 3840;           // xnT row stride
constexpr float SCALE = 0.125f;

__device__ __forceinline__ float wred_sum(float v) {
#pragma unroll
    for (int m = 32; m > 0; m >>= 1) v += __shfl_xor(v, m, 64);
    return v;
}

// ---------------------------------------------------------------------------
// Fold q/k projections: dg = q.k = qt.x_ + c
// ---------------------------------------------------------------------------
__global__ void fold_k(const float* __restrict__ qw, const float* __restrict__ qb,
                       const float* __restrict__ kw, const float* __restrict__ kb,
                       float* __restrict__ M, float* __restrict__ b2,
                       float* __restrict__ vv, float* __restrict__ cc) {
    int e = blockIdx.x, d = threadIdx.x;
    float acc = 0.f;
    for (int dp = 0; dp < 64; ++dp) acc += qw[dp * 64 + e] * kw[dp * 64 + d];
    M[e * 64 + d] = acc;
    float vp = wred_sum(qw[d * 64 + e] * kb[d]);
    if (d == 0) vv[e] = vp;
    if (e == 0) {
        float b = 0.f;
        for (int dp = 0; dp < 64; ++dp) b += qb[dp] * kw[dp * 64 + d];
        b2[d] = b;
        float cp = wred_sum(qb[d] * kb[d]);
        if (d == 0) *cc = cp;
    }
}

// ---------------------------------------------------------------------------
// LayerNorm -> xnb (bf16) + y32 (fp32, t==11 slab)
// ---------------------------------------------------------------------------
__global__ __launch_bounds__(256) void ln_k(const float* __restrict__ x,
                                            const float* __restrict__ g,
                                            const float* __restrict__ b,
                                            __bf16* __restrict__ xnb,
                                            float* __restrict__ y32) {
    int w = threadIdx.x >> 6, l = threadIdx.x & 63;
    int r = blockIdx.x * 4 + w;
    if (r >= ROWSX) return;
    float val = x[r * 64 + l];
    float mu  = wred_sum(val) * (1.f / 64.f);
    float dv  = val - mu;
    float var = wred_sum(dv * dv) * (1.f / 64.f);
    float xv  = dv * rsqrtf(var + 1e-5f) * g[l] + b[l];
    xnb[(size_t)r * 64 + l] = (__bf16)xv;
    int t = (r / NN) % TT;
    if (t == TT - 1) {
        int bbv = r / (NN * TT), n = r % NN;
        y32[(bbv * NN + n) * 64 + l] = xv;
    }
}

// ---------------------------------------------------------------------------
// Transpose xnb[b,j,d] -> xnT[b,d,j] (stride SSTR; j>=TN zero within tiles)
// ---------------------------------------------------------------------------
__global__ __launch_bounds__(256) void t_k(const __bf16* __restrict__ xnb,
                                           __bf16* __restrict__ xnT) {
    __shared__ unsigned short tile[64][65];
    int bb = blockIdx.y, j0 = blockIdx.x * 64, t = threadIdx.x;
    const unsigned short* src = (const unsigned short*)xnb;
    unsigned short* dst = (unsigned short*)xnT;
#pragma unroll
    for (int i = 0; i < 16; ++i) {
        int f = t + 256 * i, jr = f >> 6, dc = f & 63;
        int j = j0 + jr;
        tile[jr][dc] = (j < TN) ? src[((size_t)bb * TN + j) * 64 + dc] : (unsigned short)0;
    }
    __syncthreads();
#pragma unroll
    for (int i = 0; i < 16; ++i) {
        int f = t + 256 * i, d = f >> 6, jj = f & 63;
        dst[((size_t)bb * 64 + d) * SSTR + j0 + jj] = tile[jj][d];
    }
}

// ---------------------------------------------------------------------------
// qt[row] = y_ @ M + b2 (bf16);  cq[row] = y_.v + cc
// ---------------------------------------------------------------------------
__global__ __launch_bounds__(256) void qt_k(const float* __restrict__ y32,
                                            const float* __restrict__ M,
                                            const float* __restrict__ b2,
                                            const float* __restrict__ vv,
                                            const float* __restrict__ ccp,
                                            __bf16* __restrict__ qtb,
                                            float* __restrict__ cq) {
    int w = threadIdx.x >> 6, l = threadIdx.x & 63;
    int rr = blockIdx.x * 4 + w;
    if (rr >= ROWSH) return;
    float y = y32[rr * 64 + l];
    float acc = b2[l];
#pragma unroll
    for (int e = 0; e < 64; ++e) acc += __shfl(y, e, 64) * M[e * 64 + l];
    qtb[(size_t)rr * 64 + l] = (__bf16)acc;
    float cp = wred_sum(y * vv[l]);
    if (l == 0) cq[rr] = cp + *ccp;
}

// ---------------------------------------------------------------------------
// Score GEMM via MFMA. stg tile staged LDS via coalesced float4 (latency
// overlapped with MFMA). Writes sag row stride SST1, zeros for j>=TN.
// ---------------------------------------------------------------------------
__global__ __launch_bounds__(256) void score_k(const __bf16* __restrict__ qtb,
                                               const float* __restrict__ cq,
                                               const __bf16* __restrict__ xnb,
                                               const float* __restrict__ stg,
                                               __bf16* __restrict__ sag) {
    __shared__ float sstg[64 * 132];   // 33 KB, stride 132 breaks conflicts
    int bb = blockIdx.z, n0 = blockIdx.y * 64, j0 = blockIdx.x * 128;
    int t = threadIdx.x;
    int w = t >> 6, lane = t & 63;
    int m16 = lane & 15, q4 = lane >> 4;

    // ---- stage stg tile [64n x 128j] fp32 -> LDS (coalesced float4) ----
#pragma unroll
    for (int i = 0; i < 8; ++i) {
        int flat = t + i * 256;            // 0..2047
        int row = flat >> 5, c4 = (flat & 31) * 4;
        int n = n0 + row;
        float4 v = {0.f, 0.f, 0.f, 0.f};
        if (n < NN) {
            size_t rb = (size_t)(bb * NN + n) * TN;
            int j = j0 + c4;
            if (j + 3 < TN) v = *(const float4*)(stg + rb + j);
            else {
                if (j + 0 < TN) v.x = stg[rb + j + 0];
                if (j + 1 < TN) v.y = stg[rb + j + 1];
                if (j + 2 < TN) v.z = stg[rb + j + 2];
                if (j + 3 < TN) v.w = stg[rb + j + 3];
            }
        }
        *(float4*)&sstg[row * 132 + c4] = v;
    }

    // ---- MFMA: 64n x 128j, K=64 ----
    const bf16x8* ap = (const bf16x8*)(qtb + ((size_t)bb * NN + n0 + w * 16 + m16) * 64);
    bf16x8 a0 = ap[q4], a1 = ap[q4 + 4];
    f32x4 acc[8];
#pragma unroll
    for (int jt = 0; jt < 8; ++jt) {
        const bf16x8* bp = (const bf16x8*)(xnb + ((size_t)bb * TN + j0 + jt * 16 + m16) * 64);
        bf16x8 b0 = bp[q4], b1 = bp[q4 + 4];
        f32x4 c = {0.f, 0.f, 0.f, 0.f};
        c = __builtin_amdgcn_mfma_f32_16x16x32_bf16(a0, b0, c, 0, 0, 0);
        c = __builtin_amdgcn_mfma_f32_16x16x32_bf16(a1, b1, c, 0, 0, 0);
        acc[jt] = c;
    }
    int nbase = n0 + w * 16 + q4 * 4;
    float cn[4];
#pragma unroll
    for (int r = 0; r < 4; ++r) {
        int n = nbase + r;
        cn[r] = (n < NN) ? cq[bb * NN + n] : 0.f;
    }
    __syncthreads();

    // ---- epilogue: sigmoid * stg * scale ----
#pragma unroll
    for (int r = 0; r < 4; ++r) {
        int n = nbase + r;
        if (n >= NN) continue;
        int nloc = w * 16 + q4 * 4 + r;
        size_t rb = ((size_t)bb * NN + n) * SST1;
#pragma unroll
        for (int jt = 0; jt < 8; ++jt) {
            int j = j0 + jt * 16 + m16;
            float sv = sstg[nloc * 132 + jt * 16 + m16];
            float dg = (acc[jt][r] + cn[r]) * SCALE;
            float s  = 1.f / (1.f + __expf(-dg));
            float wv = (j < TN) ? s * sv * SCALE : 0.f;
            sag[rb + j] = (__bf16)wv;
        }
    }
}

// ---------------------------------------------------------------------------
// Fused topk+softmax+PV+residual. Statically-named per-row register arrays
// (va0/va1 + macro) so SROA keeps them in VGPRs — round-4's va[2][8] was
// dynamically indexed by the non-unrolled rr loop -> scratch spills (80 MB
// WRITE_SIZE). Exact threshold via binary search on [0, rowmax] bf16 keys.
// ---------------------------------------------------------------------------
__global__ __launch_bounds__(256) void attn_k(const __bf16* __restrict__ sagB,
                                              const __bf16* __restrict__ xnT,
                                              const float* __restrict__ y32,
                                              const int* __restrict__ topk_p,
                                              float* __restrict__ h) {
    __shared__ unsigned short sg[8][3720];   // 59.5 KB (normalized weights)
    __shared__ float red[4][8][64];          // 8 KB
    int t = threadIdx.x;
    int bb = blockIdx.y, n0 = blockIdx.x * 8;
    int wid = t >> 6, lane = t & 63;
    const unsigned short* sagu = (const unsigned short*)sagB;

    int topkv = *topk_p;
    bool selAll = (topkv <= 0);
    int kk = 0;
    if (!selAll) {
        kk = (topkv < 5) ? topkv * NN : topkv;
        if (kk > TN) kk = TN;
    }

    // ---- preload this wave's 2 rows into registers (coalesced b128) ----
    int r0i = wid * 2, r1i = wid * 2 + 1;
    u16x8 va0[8], va1[8];
    {
        int n = n0 + r0i;
        const u16x8* src = (const u16x8*)(sagu + (size_t)(bb * NN + n) * SST1);
#pragma unroll
        for (int ci = 0; ci < 8; ++ci) {
            int c = lane + (ci << 6);
            u16x8 v = {0, 0, 0, 0, 0, 0, 0, 0};
            if (n < NN && c < 464) v = src[c];
            va0[ci] = v;
        }
    }
    {
        int n = n0 + r1i;
        const u16x8* src = (const u16x8*)(sagu + (size_t)(bb * NN + n) * SST1);
#pragma unroll
        for (int ci = 0; ci < 8; ++ci) {
            int c = lane + (ci << 6);
            u16x8 v = {0, 0, 0, 0, 0, 0, 0, 0};
            if (n < NN && c < 464) v = src[c];
            va1[ci] = v;
        }
    }

    // ---- per-row: max, exact top-k threshold (binary search), softmax ----
#define PROC_ROW(VA, RIDX)                                                       \
    {                                                                            \
        int vmb = 0;                                                             \
        _Pragma("unroll") for (int ci = 0; ci < 8; ++ci)                         \
            _Pragma("unroll") for (int e = 0; e < 8; ++e)                        \
                vmb = max(vmb, (int)VA[ci][e]);                                  \
        _Pragma("unroll") for (int m = 32; m > 0; m >>= 1)                       \
            vmb = max(vmb, __shfl_xor(vmb, m, 64));                              \
        float vmax = __uint_as_float(((unsigned)vmb) << 16);                     \
        unsigned thrb = 0;                                                       \
        if (!selAll) {                                                           \
            unsigned lo = 0, hi = (unsigned)vmb;                                 \
            while (lo < hi) {                                                    \
                unsigned mid = (lo + hi) >> 1;                                   \
                int cnt = 0;                                                     \
                _Pragma("unroll") for (int ci = 0; ci < 8; ++ci)                 \
                    _Pragma("unroll") for (int e = 0; e < 8; ++e)                \
                        cnt += ((unsigned)VA[ci][e] > mid);                      \
                _Pragma("unroll") for (int m = 32; m > 0; m >>= 1)               \
                    cnt += __shfl_xor(cnt, m, 64);                               \
                if (cnt < kk) hi = mid; else lo = mid + 1;                       \
            }                                                                    \
            thrb = lo;                                                           \
        }                                                                        \
        float local = 0.f;                                                       \
        _Pragma("unroll") for (int ci = 0; ci < 8; ++ci) {                       \
            int c = lane + (ci << 6);                                            \
            int nvv = (c < 460) ? 8 : ((c == 460) ? 4 : 0);                      \
            _Pragma("unroll") for (int e = 0; e < 8; ++e) {                      \
                unsigned u = VA[ci][e];                                          \
                bool sel = selAll ? (e < nvv) : (u > thrb);                      \
                float ev = sel ? __expf(__uint_as_float(u << 16) - vmax) : 0.f;  \
                local += ev;                                                     \
                __bf16 eb = (__bf16)ev;                                          \
                VA[ci][e] = *(unsigned short*)&eb;                               \
            }                                                                    \
        }                                                                        \
        local = wred_sum(local);                                                 \
        bool uni = !(local > 0.f);                                               \
        float inv = uni ? 0.f : 1.f / local;                                     \
        float uval = 1.f / (float)TN;                                            \
        _Pragma("unroll") for (int ci = 0; ci < 8; ++ci) {                       \
            int c = lane + (ci << 6);                                            \
            if (c < 464) {                                                       \
                int nvv = (c < 460) ? 8 : ((c == 460) ? 4 : 0);                  \
                bf16x8 o;                                                        \
                _Pragma("unroll") for (int e = 0; e < 8; ++e) {                  \
                    if (uni) o[e] = (e < nvv) ? (__bf16)uval : (__bf16)0.f;      \
                    else {                                                       \
                        unsigned short us = VA[ci][e];                           \
                        float ev = (float)(*(__bf16*)&us);                       \
                        o[e] = (__bf16)(ev * inv);                               \
                    }                                                            \
                }                                                                \
                *(bf16x8*)&sg[RIDX][c * 8] = o;                                  \
            }                                                                    \
        }                                                                        \
    }

    PROC_ROW(va0, r0i)
    PROC_ROW(va1, r1i)
#undef PROC_ROW
    __syncthreads();

    // ---- PV: o[16][64] (rows 8..15 zero), K split across 4 waves ----
    int m16 = lane & 15, q4 = lane >> 4;
    bf16x8 zf;
#pragma unroll
    for (int e = 0; e < 8; ++e) zf[e] = (__bf16)0.f;
    f32x4 acc[4];
#pragma unroll
    for (int dt = 0; dt < 4; ++dt) acc[dt] = (f32x4){0.f, 0.f, 0.f, 0.f};
    const __bf16* bbase = xnT + (size_t)bb * 64 * SSTR;
    int kbase = wid * 928;
    for (int ks = 0; ks < 29; ++ks) {
        int k0 = kbase + ks * 32 + q4 * 8;
        bf16x8 a = zf;
        if (m16 < 8) a = *(const bf16x8*)&sg[m16][k0];
#pragma unroll
        for (int dt = 0; dt < 4; ++dt) {
            bf16x8 b = *(const bf16x8*)(bbase + (size_t)(dt * 16 + m16) * SSTR + k0);
            acc[dt] = __builtin_amdgcn_mfma_f32_16x16x32_bf16(a, b, acc[dt], 0, 0, 0);
        }
    }
#pragma unroll
    for (int dt = 0; dt < 4; ++dt)
#pragma unroll
        for (int r2 = 0; r2 < 4; ++r2) {
            int row = q4 * 4 + r2;
            if (row < 8) red[wid][row][dt * 16 + m16] = acc[dt][r2];
        }
    __syncthreads();
    // ---- cross-wave reduce + residual ----
    for (int i = t; i < 512; i += 256) {
        int row = i >> 6, col = i & 63;
        int n = n0 + row;
        if (n < NN) {
            float s = red[0][row][col] + red[1][row][col] + red[2][row][col] + red[3][row][col];
            size_t o = (size_t)(bb * NN + n) * 64 + col;
            h[o] = s + y32[o];
        }
    }
}

// ---------------------------------------------------------------------------
// FFN: out = h + (relu(LN(h)@fc1^T + b1)@fc2^T + b2)    16 rows/block
// ---------------------------------------------------------------------------
__global__ __launch_bounds__(256) void ffn_k(const float* __restrict__ h,
                                             const float* __restrict__ g,
                                             const float* __restrict__ bln,
                                             const float* __restrict__ fc1w,
                                             const float* __restrict__ fc1b,
                                             const float* __restrict__ fc2w,
                                             const float* __restrict__ fc2b,
                                             float* __restrict__ out) {
    __shared__ float zbuf[16 * 65];
    __shared__ float wbuf[256 * 65];
    __shared__ float abuf[16 * 257];
    int t = threadIdx.x;
    int r0 = blockIdx.x * 16;
    int w = t >> 6, l = t & 63;
    for (int q = 0; q < 4; ++q) {
        int rloc = w * 4 + q;
        float val = h[(r0 + rloc) * 64 + l];
        float mu  = wred_sum(val) * (1.f / 64.f);
        float dv  = val - mu;
        float var = wred_sum(dv * dv) * (1.f / 64.f);
        zbuf[rloc * 65 + l] = dv * rsqrtf(var + 1e-5f) * g[l] + bln[l];
    }
#pragma unroll
    for (int i = 0; i < 64; ++i) {
        int f = t + 256 * i, row = f >> 6, col = f & 63;
        wbuf[row * 65 + col] = fc1w[f];
    }
    __syncthreads();
    {
        int tr = t >> 6, tc = t & 63;
        float acc[4][4];
#pragma unroll
        for (int a = 0; a < 4; ++a)
#pragma unroll
            for (int c = 0; c < 4; ++c) acc[a][c] = 0.f;
#pragma unroll 4
        for (int d = 0; d < 64; ++d) {
            float av[4], bv[4];
#pragma unroll
            for (int ri = 0; ri < 4; ++ri) av[ri] = zbuf[(tr + 4 * ri) * 65 + d];
#pragma unroll
            for (int ci = 0; ci < 4; ++ci) bv[ci] = wbuf[(tc + 64 * ci) * 65 + d];
#pragma unroll
            for (int ri = 0; ri < 4; ++ri)
#pragma unroll
                for (int ci = 0; ci < 4; ++ci) acc[ri][ci] += av[ri] * bv[ci];
        }
#pragma unroll
        for (int ri = 0; ri < 4; ++ri)
#pragma unroll
            for (int ci = 0; ci < 4; ++ci) {
                int i = tc + 64 * ci;
                abuf[(tr + 4 * ri) * 257 + i] = fmaxf(acc[ri][ci] + fc1b[i], 0.f);
            }
    }
    __syncthreads();
#pragma unroll
    for (int i = 0; i < 64; ++i) {
        int f = t + 256 * i, row = f >> 8, col = f & 255;
        wbuf[row * 257 + col] = fc2w[f];
    }
    __syncthreads();
    {
        int tg = t >> 4, tc4 = t & 15;
        float acc2[4] = {0.f, 0.f, 0.f, 0.f};
#pragma unroll 8
        for (int k = 0; k < 256; ++k) {
            float a = abuf[tg * 257 + k];
#pragma unroll
            for (int ci = 0; ci < 4; ++ci) acc2[ci] += a * wbuf[(tc4 + 16 * ci) * 257 + k];
        }
#pragma unroll
        for (int ci = 0; ci < 4; ++ci) {
            int c = tc4 + 16 * ci;
            int row = r0 + tg;
            out[row * 64 + c] = h[row * 64 + c] + acc2[ci] + fc2b[c];
        }
    }
}

extern "C" void kernel_launch(void* const* d_in, const int* in_sizes, int n_in,
                              void* d_out, int out_size, void* d_ws, size_t ws_size,
                              hipStream_t stream) {
    const float* x    = (const float*)d_in[0];
    const float* stg  = (const float*)d_in[1];
    const int*   topk = (const int*)d_in[2];
    const float* qw   = (const float*)d_in[3];
    const float* qb   = (const float*)d_in[4];
    const float* kw   = (const float*)d_in[5];
    const float* kb   = (const float*)d_in[6];
    const float* lng  = (const float*)d_in[7];
    const float* lnb  = (const float*)d_in[8];
    const float* flng = (const float*)d_in[9];
    const float* flnb = (const float*)d_in[10];
    const float* fc1w = (const float*)d_in[11];
    const float* fc1b = (const float*)d_in[12];
    const float* fc2w = (const float*)d_in[13];
    const float* fc2b = (const float*)d_in[14];
    float* out = (float*)d_out;

    // Workspace layout (float units), ~55 MB total
    float* ws = (float*)d_ws;
    __bf16* xnb = (__bf16*)ws;                 // ROWSX*64 bf16 = 1,886,208 f
    float* p1   = ws + 1886208;
    __bf16* xnT = (__bf16*)p1;                 // 16*64*3840 bf16 = 1,966,080 f
    float* p2   = p1 + 1966080;
    __bf16* qtb = (__bf16*)p2;                 // 4928*64 bf16 = 157,696 f
    float* y32  = p2 + 157696;                 // 314,368 f
    float* cq   = y32 + 314368;                // 4,928 f
    float* M    = cq + 4928;                   // 4,096
    float* b2   = M + 4096;                    // 64
    float* vv   = b2 + 64;                     // 64
    float* cc   = vv + 64;                     // 16
    __bf16* sag = (__bf16*)(cc + 16);          // ROWSH*3712 bf16 = 9,116,672 f
    float* h    = (float*)sag + 9116672;       // 314,368 f

    fold_k<<<64, 64, 0, stream>>>(qw, qb, kw, kb, M, b2, vv, cc);
    ln_k<<<(ROWSX + 3) / 4, 256, 0, stream>>>(x, lng, lnb, xnb, y32);
    t_k<<<dim3((TN + 63) / 64, BB), 256, 0, stream>>>(xnb, xnT);
    qt_k<<<(ROWSH + 3) / 4, 256, 0, stream>>>(y32, M, b2, vv, cc, qtb, cq);
    score_k<<<dim3((TN + 127) / 128, (NN + 63) / 64, BB), 256, 0, stream>>>(qtb, cq, xnb, stg, sag);
    attn_k<<<dim3((NN + 7) / 8, BB), 256, 0, stream>>>(sag, xnT, y32, topk, h);
    ffn_k<<<ROWSH / 16, 256, 0, stream>>>(h, flng, flnb, fc1w, fc1b, fc2w, fc2b, out);
}